// Round 1
// baseline (351.533 us; speedup 1.0000x reference)
//
#include <hip/hip_runtime.h>
#include <hip/hip_fp16.h>

#define XDIM 256
#define YDIM 256
#define ZDIM 32
#define NT 384
#define NA 180
#define AG 4                    // angles per block
#define STRIDE 262              // halfs per LDS row (x = -1..259 -> cs = x+2 in [1,261])
#define NROWS 259               // rows y = -1..257 -> Ly = y+1 in [0,258]
#define SL_HALFS 67872          // padded up from NROWS*STRIDE = 67858 to 16B multiple
#define SL_BYTES (SL_HALFS * 2) // 135744
#define PSUM_BYTES (4 * 256 * 4)
#define SMEM_BYTES (SL_BYTES + PSUM_BYTES)

// Block: one z-slice x 4 angles. 1024 threads = 256 cols x 4 t-quarters.
// Slice staged in LDS as fp16 with a zero border so boundary handling
// (reference's valid_clip weight zeroing) falls out of pad reads for free.
__global__ __launch_bounds__(1024) void proj_kernel(
    const float* __restrict__ vol,
    const float* __restrict__ phis,
    float* __restrict__ out) {
  extern __shared__ char smem[];
  __half* sl = reinterpret_cast<__half*>(smem);
  float* psum = reinterpret_cast<float*>(smem + SL_BYTES);

  const int tid = threadIdx.x;
  const int z = blockIdx.x;   // 0..31
  const int ag = blockIdx.y;  // 0..44

  // ---- zero the slice region (establishes the zero border) ----
  {
    uint4 z4 = make_uint4(0u, 0u, 0u, 0u);
    uint4* p = reinterpret_cast<uint4*>(smem);
    for (int i = tid; i < SL_BYTES / 16; i += 1024) p[i] = z4;
  }
  __syncthreads();

  // ---- stage slice z as fp16: data row y at Ly=y+1, data col x at cs=x+2 ----
  {
    const float4* s4 = reinterpret_cast<const float4*>(vol + z * (YDIM * XDIM));
    int k = (tid >> 6) * 1024 + (tid & 63);  // wave-contiguous, lane-coalesced
#pragma unroll
    for (int i = 0; i < 16; ++i, k += 64) {
      float4 v = s4[k];
      int fidx = k << 2;
      int r = fidx >> 8;
      int x = fidx & 255;
      __half2* d = reinterpret_cast<__half2*>(sl + (r + 1) * STRIDE + (x + 2));
      d[0] = __floats2half2_rn(v.x, v.y);
      d[1] = __floats2half2_rn(v.z, v.w);
    }
  }
  __syncthreads();

  const int col = tid & 255;
  const int q = tid >> 8;  // t-quarter (interleaved mod 4 for load balance)
  const float u = (float)col - 127.5f;

  for (int j = 0; j < AG; ++j) {
    const int a = ag * AG + j;
    const float phi = phis[a] * 0.017453292519943295f;
    const float c = cosf(phi);
    const float s = sinf(phi);
    // ix(t) = bx + t*c, iy(t) = by + t*s, t = it - 191.5
    const float bx = fmaf(u, -s, 127.5f);
    const float by = fmaf(u, c, 127.5f);

    // t-interval where the sample can be nonzero: ix,iy in (-1,256). Widen +-2;
    // every executed sample is exact (clamp + zero pad), so widening is safe.
    float lo = 0.f, hi = (float)NT;
    {
      float d = c;
      if (fabsf(d) < 1e-6f) {
        if (bx <= -1.f || bx >= 256.f) { lo = 1.f; hi = 0.f; }
      } else {
        float t1 = (-1.f - bx) / d + 191.5f;
        float t2 = (256.f - bx) / d + 191.5f;
        lo = fmaxf(lo, fminf(t1, t2) - 2.f);
        hi = fminf(hi, fmaxf(t1, t2) + 2.f);
      }
    }
    {
      float d = s;
      if (fabsf(d) < 1e-6f) {
        if (by <= -1.f || by >= 256.f) { lo = 1.f; hi = 0.f; }
      } else {
        float t1 = (-1.f - by) / d + 191.5f;
        float t2 = (256.f - by) / d + 191.5f;
        lo = fmaxf(lo, fminf(t1, t2) - 2.f);
        hi = fminf(hi, fmaxf(t1, t2) + 2.f);
      }
    }
    int itlo = (int)fmaxf(lo, 0.f);
    int ithi = (int)fminf(hi, (float)NT);
    int start = itlo + ((q - itlo) & 3);  // first it >= itlo with it % 4 == q

    float acc = 0.f;
    float t = (float)start - 191.5f;  // half-integers: t += 4 stays exact in fp32
    for (int it = start; it < ithi; it += 4, t += 4.f) {
      float x = fmaf(t, c, bx);
      float y = fmaf(t, s, by);
      x = fminf(fmaxf(x, -1.f), 256.5f);
      y = fminf(fmaxf(y, -1.f), 256.5f);
      float x0f = floorf(x);
      float y0f = floorf(y);
      float fx = x - x0f;
      float fy = y - y0f;
      // half index of (y0,x0): (y0+1)*262 + (x0+2); fma is exact (ints < 2^24)
      int idx = (int)fmaf(y0f, (float)STRIDE, x0f) + (STRIDE + 2);
      const __half* p = sl + idx;
      float v00 = __half2float(p[0]);
      float v01 = __half2float(p[1]);
      float v10 = __half2float(p[STRIDE]);
      float v11 = __half2float(p[STRIDE + 1]);
      float wx0 = 1.f - fx;
      float h0 = fmaf(v01, fx, v00 * wx0);
      float h1 = fmaf(v11, fx, v10 * wx0);
      acc = fmaf(h0, 1.f - fy, acc);
      acc = fmaf(h1, fy, acc);
    }
    psum[tid] = acc;
    __syncthreads();
    if (tid < 256) {
      float r = psum[col] + psum[256 + col] + psum[512 + col] + psum[768 + col];
      out[(a * ZDIM + z) * XDIM + col] = r;
    }
    __syncthreads();
  }
}

extern "C" void kernel_launch(void* const* d_in, const int* in_sizes, int n_in,
                              void* d_out, int out_size, void* d_ws, size_t ws_size,
                              hipStream_t stream) {
  const float* vol = (const float*)d_in[0];
  const float* phis = (const float*)d_in[1];
  float* out = (float*)d_out;
  // Opt in to >64KB dynamic LDS (idempotent; host-side, not stream-captured).
  (void)hipFuncSetAttribute((const void*)proj_kernel,
                            hipFuncAttributeMaxDynamicSharedMemorySize,
                            SMEM_BYTES);
  dim3 grid(ZDIM, NA / AG);
  proj_kernel<<<grid, 1024, SMEM_BYTES, stream>>>(vol, phis, out);
}